// Round 25
// baseline (109.179 us; speedup 1.0000x reference)
//
#include <hip/hip_runtime.h>

typedef __attribute__((ext_vector_type(8))) _Float16 half8;
typedef __attribute__((ext_vector_type(8))) unsigned short u16x8;
typedef __attribute__((ext_vector_type(4))) unsigned short u16x4;
typedef __attribute__((ext_vector_type(4))) float f32x4;

#define NEGV (-1e30f)

// ---------------------------------------------------------------------------
// Workspace layout (bytes):
//  Bf  : [1152][1024] fp16 @ 0          (2,359,296)
//  LR  : [48][8192]  f32   @ 21495808   (1,572,864)
//  Vt  : [8][16][128][512] fp16 @ 23068672 (16,777,216)
//  adjB: [16][512][512] u8 @ 39845888   (4,194,304)
// ---------------------------------------------------------------------------

__device__ __forceinline__ unsigned short f2h(float f) {
    union { _Float16 h; unsigned short u; } c;
    c.h = (_Float16)f;
    return c.u;
}
__device__ __forceinline__ float h2f(unsigned short u) {
    union { _Float16 h; unsigned short u; } c;
    c.u = u;
    return (float)c.h;
}

// ---------------------------------------------------------------------------
// Kernel 1: fused prep (adj->bytes + pack tr/wa/zero).  grid 1616. [verified]
// ---------------------------------------------------------------------------
__global__ __launch_bounds__(256) void prep_kernel(const int* __restrict__ adj,
                                                   const float* __restrict__ W,
                                                   const float* __restrict__ a1,
                                                   const float* __restrict__ a2,
                                                   unsigned short* __restrict__ Bf,
                                                   unsigned char* __restrict__ adjB) {
    __shared__ float tile[64 * 133];
    const int bid = blockIdx.x;
    const int tid = threadIdx.x;

    if (bid < 1024) {
        const int idx = bid * 256 + tid;
        const int4* s = (const int4*)(adj + (size_t)idx * 16);
        int4 v0 = s[0], v1 = s[1], v2 = s[2], v3 = s[3];
        union { unsigned char c[16]; int4 v; } o;
        o.c[0] = (unsigned char)v0.x; o.c[1] = (unsigned char)v0.y;
        o.c[2] = (unsigned char)v0.z; o.c[3] = (unsigned char)v0.w;
        o.c[4] = (unsigned char)v1.x; o.c[5] = (unsigned char)v1.y;
        o.c[6] = (unsigned char)v1.z; o.c[7] = (unsigned char)v1.w;
        o.c[8] = (unsigned char)v2.x; o.c[9] = (unsigned char)v2.y;
        o.c[10] = (unsigned char)v2.z; o.c[11] = (unsigned char)v2.w;
        o.c[12] = (unsigned char)v3.x; o.c[13] = (unsigned char)v3.y;
        o.c[14] = (unsigned char)v3.z; o.c[15] = (unsigned char)v3.w;
        *(int4*)(adjB + (size_t)idx * 16) = o.v;
    } else if (bid < 1152) {
        const int pb = bid - 1024;
        const int kt = pb & 15, h = pb >> 4;
        const int k0 = kt * 64;
        const float* wsrc = W + ((size_t)((h * 3 + 2) * 1024) + k0) * 128;

        #pragma unroll
        for (int rep = 0; rep < 8; ++rep) {
            int idx = rep * 256 + tid;
            int k = idx >> 5, dc = (idx & 31) * 4;
            float4 v = *(const float4*)(wsrc + (size_t)k * 128 + dc);
            tile[k * 133 + dc + 0] = v.x;
            tile[k * 133 + dc + 1] = v.y;
            tile[k * 133 + dc + 2] = v.z;
            tile[k * 133 + dc + 3] = v.w;
        }
        __syncthreads();
        #pragma unroll
        for (int rep = 0; rep < 4; ++rep) {
            int idx = rep * 256 + tid;
            int d = idx >> 3, kc = (idx & 7) * 8;
            u16x8 vh;
            #pragma unroll
            for (int q = 0; q < 8; ++q) vh[q] = f2h(tile[(kc + q) * 133 + d]);
            *(u16x8*)(Bf + (size_t)(h * 128 + d) * 1024 + k0 + kc) = vh;
        }
    } else if (bid < 1536) {
        const int pb = bid - 1152;
        const int kt = pb & 15, ht = pb >> 4;
        const int h = ht & 7, t = ht >> 3;
        const int k0 = kt * 64;
        const float* wsrc = W + ((size_t)((h * 3 + t) * 1024) + k0) * 128;

        #pragma unroll
        for (int rep = 0; rep < 8; ++rep) {
            int idx = rep * 256 + tid;
            int k = idx >> 5, dc = (idx & 31) * 4;
            float4 v = *(const float4*)(wsrc + (size_t)k * 128 + dc);
            tile[k * 133 + dc + 0] = v.x;
            tile[k * 133 + dc + 1] = v.y;
            tile[k * 133 + dc + 2] = v.z;
            tile[k * 133 + dc + 3] = v.w;
        }
        __syncthreads();
        if (tid < 128) {
            const int k = tid & 63, s = tid >> 6;
            const float* ar = (s ? a2 : a1) + (h * 3 + t) * 128;
            float acc = 0.f;
            #pragma unroll 4
            for (int d = 0; d < 128; ++d) acc += tile[k * 133 + d] * ar[d];
            Bf[(size_t)(1024 + s * 24 + t * 8 + h) * 1024 + k0 + k] = f2h(acc);
        }
    } else {
        const int n = 1072 + (bid - 1536);
        *(unsigned long long*)(Bf + (size_t)n * 1024 + tid * 4) = 0ull;
    }
}

// ---------------------------------------------------------------------------
// Kernel 2: fp16 MFMA GEMM — T4 pipeline, B now 2 STEPS DEEP (Bfs[3]):
//   step t issues B(t+2)+X(t+2); barrier = vmcnt(6) (B(t+1) already drained
//   by CONVA's wait on X(t+1): 6 newer ops in flight). 6-step static unroll.
// ---------------------------------------------------------------------------
__global__ __launch_bounds__(256, 3) void mgemm(const float* __restrict__ X,
                                                const unsigned short* __restrict__ Bf,
                                                const float* __restrict__ nm,
                                                unsigned short* __restrict__ Vt,
                                                float* __restrict__ LR) {
    __shared__ unsigned short Ah[2][128 * 32];
    __shared__ unsigned short Bfs[3][128 * 32];

    const int bid = blockIdx.x;                 // 0..575
    const int swz = (bid & 7) * 72 + (bid >> 3); // XCD-aware, bijective
    const int nt = swz % 9, mt = swz / 9;
    const int n0 = nt * 128, m0 = mt * 128;

    const int tid = threadIdx.x;
    const int lane = tid & 63, w = tid >> 6;
    const int wr = w >> 1, wc = w & 1;
    const int fr = lane & 15, fq = lane >> 4;

    f32x4 acc[4][4];
    #pragma unroll
    for (int m = 0; m < 4; ++m)
        #pragma unroll
        for (int n = 0; n < 4; ++n) acc[m][n] = (f32x4){0.f, 0.f, 0.f, 0.f};

    const int arow = tid >> 1, ahalf = tid & 1;
    const float* xs = X + (size_t)(m0 + arow) * 1024 + ahalf * 16;
    const int aoff = arow * 32 + ahalf * 16;

#define GLDB(kk, buf) do {                                                        \
        _Pragma("unroll")                                                          \
        for (int q_ = 0; q_ < 2; ++q_) {                                           \
            const int s_ = q_ * 256 + tid;                                         \
            const int brow_ = s_ >> 2, bkb_ = s_ & 3;                              \
            const unsigned short* g_ = Bf + (size_t)(n0 + brow_) * 1024 + (kk) + bkb_ * 8; \
            unsigned short* d_ = &Bfs[buf][(q_ * 256 + w * 64) * 8];               \
            __builtin_amdgcn_global_load_lds(                                      \
                (const __attribute__((address_space(1))) void*)g_,                 \
                (__attribute__((address_space(3))) void*)d_, 16, 0, 0);            \
        }                                                                          \
    } while (0)

#define CONVA(xa_, xb_, xc_, xd_, buf) do {                                       \
        float xf_[16] = {(xa_).x, (xa_).y, (xa_).z, (xa_).w,                       \
                         (xb_).x, (xb_).y, (xb_).z, (xb_).w,                       \
                         (xc_).x, (xc_).y, (xc_).z, (xc_).w,                       \
                         (xd_).x, (xd_).y, (xd_).z, (xd_).w};                      \
        u16x8 v0_, v1_;                                                            \
        _Pragma("unroll")                                                          \
        for (int i_ = 0; i_ < 8; ++i_) v0_[i_] = f2h(xf_[i_]);                     \
        _Pragma("unroll")                                                          \
        for (int i_ = 0; i_ < 8; ++i_) v1_[i_] = f2h(xf_[8 + i_]);                 \
        *(u16x8*)(&Ah[buf][aoff]) = v0_;                                           \
        *(u16x8*)(&Ah[buf][aoff + 8]) = v1_;                                       \
    } while (0)

#define COMPUTE(abuf, bbuf) do {                                                  \
        half8 am_[4], bn_[4];                                                      \
        _Pragma("unroll")                                                          \
        for (int m_ = 0; m_ < 4; ++m_)                                             \
            am_[m_] = *(half8*)(&Ah[abuf][(wr * 64 + m_ * 16 + fr) * 32 + fq * 8]);\
        _Pragma("unroll")                                                          \
        for (int n_ = 0; n_ < 4; ++n_)                                             \
            bn_[n_] = *(half8*)(&Bfs[bbuf][(wc * 64 + n_ * 16 + fr) * 32 + fq * 8]);\
        _Pragma("unroll")                                                          \
        for (int m_ = 0; m_ < 4; ++m_)                                             \
            _Pragma("unroll")                                                      \
            for (int n_ = 0; n_ < 4; ++n_)                                         \
                acc[m_][n_] = __builtin_amdgcn_mfma_f32_16x16x32_f16(am_[m_], bn_[n_], acc[m_][n_], 0, 0, 0); \
    } while (0)

#define XLOAD(set_a, set_b, set_c, set_d, col) do {                               \
        set_a = *(const float4*)(xs + (col));                                      \
        set_b = *(const float4*)(xs + (col) + 4);                                  \
        set_c = *(const float4*)(xs + (col) + 8);                                  \
        set_d = *(const float4*)(xs + (col) + 12);                                 \
    } while (0)

#define PIPE_BAR6() asm volatile("s_waitcnt vmcnt(6) lgkmcnt(0)\n\ts_barrier" ::: "memory")
#define PIPE_BAR0() asm volatile("s_waitcnt vmcnt(0) lgkmcnt(0)\n\ts_barrier" ::: "memory")

// one pipeline step at static t: issues B(t+2), X(t+2); computes t; converts X(t+1)
#define STEP(colT2, bcur, b2, abufCur, abufNxt, XLC_a,XLC_b,XLC_c,XLC_d, XLN_a,XLN_b,XLN_c,XLN_d) do { \
        GLDB(colT2, b2);                                                           \
        __builtin_amdgcn_sched_barrier(0);                                         \
        XLOAD(XLN_a, XLN_b, XLN_c, XLN_d, colT2);                                  \
        __builtin_amdgcn_sched_barrier(0);                                         \
        COMPUTE(abufCur, bcur);                                                    \
        CONVA(XLC_a, XLC_b, XLC_c, XLC_d, abufNxt);                                \
        PIPE_BAR6();                                                               \
    } while (0)

    float4 x0a, x0b, x0c, x0d, x1a, x1b, x1c, x1d;

    // ---- prologue: X(0), B(0), B(1); convert X(0)->Ah[0]; X(1); bar vmcnt(6)
    XLOAD(x0a, x0b, x0c, x0d, 0);
    __builtin_amdgcn_sched_barrier(0);
    GLDB(0, 0);
    GLDB(32, 1);
    __builtin_amdgcn_sched_barrier(0);
    CONVA(x0a, x0b, x0c, x0d, 0);       // waits X(0); B(0),B(1) stay in flight
    XLOAD(x1a, x1b, x1c, x1d, 32);
    PIPE_BAR6();                        // drains B(0); B(1)+X(1)=6 in flight

    // ---- main loop: t = 0..29 as 5 iterations of 6 static steps
    for (int kc = 0; kc < 960; kc += 192) {
        // s=0: t%3=0, (t+2)%3=2, Ah cur 0 -> next 1; conva set1; load set0
        STEP(kc + 64,  0, 2, 0, 1, x1a,x1b,x1c,x1d, x0a,x0b,x0c,x0d);
        // s=1: bcur1 b2=0; Ah 1->0; conva set0; load set1
        STEP(kc + 96,  1, 0, 1, 0, x0a,x0b,x0c,x0d, x1a,x1b,x1c,x1d);
        // s=2: bcur2 b2=1; Ah 0->1; conva set1; load set0
        STEP(kc + 128, 2, 1, 0, 1, x1a,x1b,x1c,x1d, x0a,x0b,x0c,x0d);
        // s=3: bcur0 b2=2; Ah 1->0; conva set0; load set1
        STEP(kc + 160, 0, 2, 1, 0, x0a,x0b,x0c,x0d, x1a,x1b,x1c,x1d);
        // s=4: bcur1 b2=0; Ah 0->1; conva set1; load set0
        STEP(kc + 192, 1, 0, 0, 1, x1a,x1b,x1c,x1d, x0a,x0b,x0c,x0d);
        // s=5: bcur2 b2=1; Ah 1->0; conva set0; load set1
        STEP(kc + 224, 2, 1, 1, 0, x0a,x0b,x0c,x0d, x1a,x1b,x1c,x1d);
    }

    // ---- tail: t=30 (Ah0, Bfs0), t=31 (Ah1, Bfs1)
    COMPUTE(0, 0);                       // col 960
    CONVA(x1a, x1b, x1c, x1d, 1);        // X col 992 -> Ah[1]
    PIPE_BAR0();                         // drain everything
    COMPUTE(1, 1);                       // col 992

#undef GLDB
#undef CONVA
#undef COMPUTE
#undef XLOAD
#undef PIPE_BAR6
#undef PIPE_BAR0
#undef STEP

    // ---- epilogue: C/D layout col=lane&15, row=(lane>>4)*4+reg
    if (nt < 8) {
        const int b_ = (mt * 128) >> 9;
        const int jb0 = (mt & 3) * 128;
        unsigned short* vtw = Vt + (size_t)(nt * 16 + b_) * 128 * 512;
        #pragma unroll
        for (int m = 0; m < 4; ++m) {
            const int jb = jb0 + wr * 64 + m * 16 + fq * 4;
            float mk[4];
            #pragma unroll
            for (int r = 0; r < 4; ++r)
                mk[r] = nm[m0 + wr * 64 + m * 16 + fq * 4 + r];
            #pragma unroll
            for (int n = 0; n < 4; ++n) {
                const int d = wc * 64 + n * 16 + fr;
                u16x4 pk;
                #pragma unroll
                for (int r = 0; r < 4; ++r) pk[r] = f2h(acc[m][n][r] * mk[r]);
                *(u16x4*)(vtw + (size_t)d * 512 + jb) = pk;
            }
        }
    } else {
        #pragma unroll
        for (int m = 0; m < 4; ++m) {
            #pragma unroll
            for (int r = 0; r < 4; ++r) {
                const int R = m0 + wr * 64 + m * 16 + fq * 4 + r;
                #pragma unroll
                for (int n = 0; n < 4; ++n) {
                    const int c = wc * 64 + n * 16 + fr;
                    if (c < 48) LR[(size_t)c * 8192 + R] = acc[m][n][r];
                }
            }
        }
    }
}

// ---------------------------------------------------------------------------
// Kernel 4: fused attn — r22 structure; in-loop barrier now vmcnt(2)
//   (STAGE_V drained, adj prefetch crosses the barrier).
// ---------------------------------------------------------------------------
__global__ __launch_bounds__(256, 4) void attn_kernel(const unsigned short* __restrict__ Vt,
                                                      const float* __restrict__ LR,
                                                      const unsigned char* __restrict__ adjB,
                                                      float* __restrict__ out) {
    __shared__ __align__(16) unsigned short Vb[2][16 * 512];
    __shared__ __align__(16) float rt[3 * 512];

    const int bid = blockIdx.x;
    const int itg = bid >> 7, hb = bid & 127, h = hb >> 4, b = hb & 15;
    const int tid = threadIdx.x, w = tid >> 6, lane = tid & 63;
    const int fr = lane & 15, fq = lane >> 4;
    const int i0 = (itg * 4 + w) * 16;
    const int fq8 = fq * 8;

    for (int idx = tid; idx < 1536; idx += 256) {
        int t = idx >> 9, j = idx & 511;
        rt[idx] = LR[(size_t)(24 + t * 8 + h) * 8192 + b * 512 + j];
    }
    const float lf0 = LR[(size_t)(h) * 8192 + b * 512 + i0 + fr];
    const float lf1 = LR[(size_t)(8 + h) * 8192 + b * 512 + i0 + fr];
    const float lf2 = LR[(size_t)(16 + h) * 8192 + b * 512 + i0 + fr];
    const unsigned char* arow = adjB + (size_t)(b * 512 + i0 + fr) * 512;
    const unsigned short* vt = Vt + (size_t)(h * 16 + b) * 128 * 512;

#define STAGE_V(bufp, os_) do {                                                   \
        _Pragma("unroll")                                                          \
        for (int q_ = 0; q_ < 4; ++q_) {                                           \
            const int nh_ = q_ * 4 + w;                                            \
            const unsigned short* src_ = vt + (size_t)((nh_ >> 1) * 16 + fr) * 512 \
                                          + (os_) * 64 + (nh_ & 1) * 32 + fq8;     \
            unsigned short* dst_ = (bufp) + nh_ * 512;                             \
            __builtin_amdgcn_global_load_lds(                                      \
                (const __attribute__((address_space(1))) void*)src_,               \
                (__attribute__((address_space(3))) void*)dst_, 16, 0, 0);          \
        }                                                                          \
    } while (0)

#define ATTN_BAR2() asm volatile("s_waitcnt vmcnt(2) lgkmcnt(0)\n\ts_barrier" ::: "memory")

    STAGE_V(&Vb[0][0], 0);
    uint2 aA = *(const uint2*)(arow + fq8);
    uint2 aB = *(const uint2*)(arow + fq8 + 32);

    f32x4 acc[8];
    #pragma unroll
    for (int n = 0; n < 8; ++n) acc[n] = (f32x4){0.f, 0.f, 0.f, 0.f};
    float rsum = 0.f;

    __syncthreads();

    #pragma unroll 1
    for (int os = 0; os < 8; ++os) {
        unsigned short* vb = &Vb[os & 1][0];
        if (os < 7) STAGE_V(&Vb[(os & 1) ^ 1][0], os + 1);

        const int jA = os * 64 + fq8;
        const int jB = jA + 32;

        u16x8 vhA, vhB;
        {
            float4 r0a = *(const float4*)(rt + jA), r0b = *(const float4*)(rt + jA + 4);
            float4 r1a = *(const float4*)(rt + 512 + jA), r1b = *(const float4*)(rt + 512 + jA + 4);
            float4 r2a = *(const float4*)(rt + 1024 + jA), r2b = *(const float4*)(rt + 1024 + jA + 4);
            float e0[8] = {r0a.x, r0a.y, r0a.z, r0a.w, r0b.x, r0b.y, r0b.z, r0b.w};
            float e1[8] = {r1a.x, r1a.y, r1a.z, r1a.w, r1b.x, r1b.y, r1b.z, r1b.w};
            float e2[8] = {r2a.x, r2a.y, r2a.z, r2a.w, r2b.x, r2b.y, r2b.z, r2b.w};
            #pragma unroll
            for (int q = 0; q < 8; ++q) {
                unsigned av = ((q < 4 ? aA.x : aA.y) >> (8 * (q & 3))) & 255u;
                float sb = (av == 1u) ? (lf0 + e0[q])
                         : (av == 2u) ? (lf1 + e1[q]) : (lf2 + e2[q]);
                float sv = fmaxf(sb, 0.f) + 0.2f * fminf(sb, 0.f);
                float p = (av != 0u) ? __expf(sv) : 0.f;
                rsum += p;
                vhA[q] = f2h(p);
            }
        }
        {
            float4 r0a = *(const float4*)(rt + jB), r0b = *(const float4*)(rt + jB + 4);
            float4 r1a = *(const float4*)(rt + 512 + jB), r1b = *(const float4*)(rt + 512 + jB + 4);
            float4 r2a = *(const float4*)(rt + 1024 + jB), r2b = *(const float4*)(rt + 1024 + jB + 4);
            float e0[8] = {r0a.x, r0a.y, r0a.z, r0a.w, r0b.x, r0b.y, r0b.z, r0b.w};
            float e1[8] = {r1a.x, r1a.y, r1a.z, r1a.w, r1b.x, r1b.y, r1b.z, r1b.w};
            float e2[8] = {r2a.x, r2a.y, r2a.z, r2a.w, r2b.x, r2b.y, r2b.z, r2b.w};
            #pragma unroll
            for (int q = 0; q < 8; ++q) {
                unsigned av = ((q < 4 ? aB.x : aB.y) >> (8 * (q & 3))) & 255u;
                float sb = (av == 1u) ? (lf0 + e0[q])
                         : (av == 2u) ? (lf1 + e1[q]) : (lf2 + e2[q]);
                float sv = fmaxf(sb, 0.f) + 0.2f * fminf(sb, 0.f);
                float p = (av != 0u) ? __expf(sv) : 0.f;
                rsum += p;
                vhB[q] = f2h(p);
            }
        }
        if (os < 7) {
            aA = *(const uint2*)(arow + (os + 1) * 64 + fq8);
            aB = *(const uint2*)(arow + (os + 1) * 64 + fq8 + 32);
        }

        half8 ahA = *(half8*)&vhA, ahB = *(half8*)&vhB;

        #pragma unroll
        for (int n = 0; n < 8; ++n) {
            half8 vA = *(half8*)(vb + (n * 2 + 0) * 512 + lane * 8);
            half8 vB = *(half8*)(vb + (n * 2 + 1) * 512 + lane * 8);
            acc[n] = __builtin_amdgcn_mfma_f32_16x16x32_f16(ahA, vA, acc[n], 0, 0, 0);
            acc[n] = __builtin_amdgcn_mfma_f32_16x16x32_f16(ahB, vB, acc[n], 0, 0, 0);
        }
        ATTN_BAR2();   // STAGE_V(os+1) drained; adj(os+2) prefetch crosses
    }
#undef STAGE_V
#undef ATTN_BAR2

    rsum += __shfl_xor(rsum, 16);
    rsum += __shfl_xor(rsum, 32);

    #pragma unroll
    for (int rr = 0; rr < 4; ++rr) {
        const int row = fq * 4 + rr;
        const float inv = 1.0f / __shfl(rsum, row);
        #pragma unroll
        for (int n = 0; n < 8; ++n) {
            out[(size_t)(b * 512 + i0 + row) * 1024 + h * 128 + n * 16 + fr] =
                fmaxf(acc[n][rr] * inv, 0.f);
        }
    }
}

// ---------------------------------------------------------------------------
extern "C" void kernel_launch(void* const* d_in, const int* in_sizes, int n_in,
                              void* d_out, int out_size, void* d_ws, size_t ws_size,
                              hipStream_t stream) {
    const float* x   = (const float*)d_in[0];
    const int*   adj = (const int*)d_in[1];
    const float* nm  = (const float*)d_in[2];
    const float* W   = (const float*)d_in[3];
    const float* a1  = (const float*)d_in[4];
    const float* a2  = (const float*)d_in[5];
    float* out = (float*)d_out;
    char* wsb = (char*)d_ws;

    unsigned short* Bf   = (unsigned short*)(wsb);
    float*          LR   = (float*)(wsb + 21495808);
    unsigned short* Vt   = (unsigned short*)(wsb + 23068672);
    unsigned char*  adjB = (unsigned char*)(wsb + 39845888);

    hipLaunchKernelGGL(prep_kernel, dim3(1616), dim3(256), 0, stream, adj, W, a1, a2, Bf, adjB);
    hipLaunchKernelGGL(mgemm, dim3(576), dim3(256), 0, stream, x, Bf, nm, Vt, LR);
    hipLaunchKernelGGL(attn_kernel, dim3(1024), dim3(256), 0, stream, Vt, LR, adjB, out);
}

// Round 26
// 96.820 us; speedup vs baseline: 1.1277x; 1.1277x over previous
//
#include <hip/hip_runtime.h>

typedef __attribute__((ext_vector_type(8))) _Float16 half8;
typedef __attribute__((ext_vector_type(8))) unsigned short u16x8;
typedef __attribute__((ext_vector_type(4))) unsigned short u16x4;
typedef __attribute__((ext_vector_type(4))) float f32x4;

#define NEGV (-1e30f)

// ---------------------------------------------------------------------------
// Workspace layout (bytes):
//  Bf  : [1152][1024] fp16 @ 0          (2,359,296)
//  LR  : [48][8192]  f32   @ 21495808   (1,572,864)
//  Vt  : [8][16][128][512] fp16 @ 23068672 (16,777,216)
//  adjB: [16][512][512] u8 @ 39845888   (4,194,304)
// ---------------------------------------------------------------------------

__device__ __forceinline__ unsigned short f2h(float f) {
    union { _Float16 h; unsigned short u; } c;
    c.h = (_Float16)f;
    return c.u;
}
__device__ __forceinline__ float h2f(unsigned short u) {
    union { _Float16 h; unsigned short u; } c;
    c.u = u;
    return (float)c.h;
}

// ---------------------------------------------------------------------------
// Kernel 1: fused prep (adj->bytes + pack tr/wa/zero).  grid 1616. [verified]
// ---------------------------------------------------------------------------
__global__ __launch_bounds__(256) void prep_kernel(const int* __restrict__ adj,
                                                   const float* __restrict__ W,
                                                   const float* __restrict__ a1,
                                                   const float* __restrict__ a2,
                                                   unsigned short* __restrict__ Bf,
                                                   unsigned char* __restrict__ adjB) {
    __shared__ float tile[64 * 133];
    const int bid = blockIdx.x;
    const int tid = threadIdx.x;

    if (bid < 1024) {
        const int idx = bid * 256 + tid;
        const int4* s = (const int4*)(adj + (size_t)idx * 16);
        int4 v0 = s[0], v1 = s[1], v2 = s[2], v3 = s[3];
        union { unsigned char c[16]; int4 v; } o;
        o.c[0] = (unsigned char)v0.x; o.c[1] = (unsigned char)v0.y;
        o.c[2] = (unsigned char)v0.z; o.c[3] = (unsigned char)v0.w;
        o.c[4] = (unsigned char)v1.x; o.c[5] = (unsigned char)v1.y;
        o.c[6] = (unsigned char)v1.z; o.c[7] = (unsigned char)v1.w;
        o.c[8] = (unsigned char)v2.x; o.c[9] = (unsigned char)v2.y;
        o.c[10] = (unsigned char)v2.z; o.c[11] = (unsigned char)v2.w;
        o.c[12] = (unsigned char)v3.x; o.c[13] = (unsigned char)v3.y;
        o.c[14] = (unsigned char)v3.z; o.c[15] = (unsigned char)v3.w;
        *(int4*)(adjB + (size_t)idx * 16) = o.v;
    } else if (bid < 1152) {
        const int pb = bid - 1024;
        const int kt = pb & 15, h = pb >> 4;
        const int k0 = kt * 64;
        const float* wsrc = W + ((size_t)((h * 3 + 2) * 1024) + k0) * 128;

        #pragma unroll
        for (int rep = 0; rep < 8; ++rep) {
            int idx = rep * 256 + tid;
            int k = idx >> 5, dc = (idx & 31) * 4;
            float4 v = *(const float4*)(wsrc + (size_t)k * 128 + dc);
            tile[k * 133 + dc + 0] = v.x;
            tile[k * 133 + dc + 1] = v.y;
            tile[k * 133 + dc + 2] = v.z;
            tile[k * 133 + dc + 3] = v.w;
        }
        __syncthreads();
        #pragma unroll
        for (int rep = 0; rep < 4; ++rep) {
            int idx = rep * 256 + tid;
            int d = idx >> 3, kc = (idx & 7) * 8;
            u16x8 vh;
            #pragma unroll
            for (int q = 0; q < 8; ++q) vh[q] = f2h(tile[(kc + q) * 133 + d]);
            *(u16x8*)(Bf + (size_t)(h * 128 + d) * 1024 + k0 + kc) = vh;
        }
    } else if (bid < 1536) {
        const int pb = bid - 1152;
        const int kt = pb & 15, ht = pb >> 4;
        const int h = ht & 7, t = ht >> 3;
        const int k0 = kt * 64;
        const float* wsrc = W + ((size_t)((h * 3 + t) * 1024) + k0) * 128;

        #pragma unroll
        for (int rep = 0; rep < 8; ++rep) {
            int idx = rep * 256 + tid;
            int k = idx >> 5, dc = (idx & 31) * 4;
            float4 v = *(const float4*)(wsrc + (size_t)k * 128 + dc);
            tile[k * 133 + dc + 0] = v.x;
            tile[k * 133 + dc + 1] = v.y;
            tile[k * 133 + dc + 2] = v.z;
            tile[k * 133 + dc + 3] = v.w;
        }
        __syncthreads();
        if (tid < 128) {
            const int k = tid & 63, s = tid >> 6;
            const float* ar = (s ? a2 : a1) + (h * 3 + t) * 128;
            float acc = 0.f;
            #pragma unroll 4
            for (int d = 0; d < 128; ++d) acc += tile[k * 133 + d] * ar[d];
            Bf[(size_t)(1024 + s * 24 + t * 8 + h) * 1024 + k0 + k] = f2h(acc);
        }
    } else {
        const int n = 1072 + (bid - 1536);
        *(unsigned long long*)(Bf + (size_t)n * 1024 + tid * 4) = 0ull;
    }
}

// ---------------------------------------------------------------------------
// Kernel 2: fp16 MFMA GEMM — r24-exact (verified 57us): counted-vmcnt raw
//   barrier (T4): per step issue B(t+1) [2 vmem] + X(t+2) [4 vmem],
//   compute(t), convert X(t+1); `s_waitcnt vmcnt(4); s_barrier` — B(t+1)
//   drained, X(t+2) crosses. Manual 2x unroll -> static indices.
// ---------------------------------------------------------------------------
__global__ __launch_bounds__(256, 3) void mgemm(const float* __restrict__ X,
                                                const unsigned short* __restrict__ Bf,
                                                const float* __restrict__ nm,
                                                unsigned short* __restrict__ Vt,
                                                float* __restrict__ LR) {
    __shared__ unsigned short Ah[2][128 * 32];
    __shared__ unsigned short Bfs[2][128 * 32];

    const int bid = blockIdx.x;                 // 0..575
    const int swz = (bid & 7) * 72 + (bid >> 3); // XCD-aware, bijective
    const int nt = swz % 9, mt = swz / 9;
    const int n0 = nt * 128, m0 = mt * 128;

    const int tid = threadIdx.x;
    const int lane = tid & 63, w = tid >> 6;
    const int wr = w >> 1, wc = w & 1;
    const int fr = lane & 15, fq = lane >> 4;

    f32x4 acc[4][4];
    #pragma unroll
    for (int m = 0; m < 4; ++m)
        #pragma unroll
        for (int n = 0; n < 4; ++n) acc[m][n] = (f32x4){0.f, 0.f, 0.f, 0.f};

    const int arow = tid >> 1, ahalf = tid & 1;
    const float* xs = X + (size_t)(m0 + arow) * 1024 + ahalf * 16;
    const int aoff = arow * 32 + ahalf * 16;

#define GLDB(kk, buf) do {                                                        \
        _Pragma("unroll")                                                          \
        for (int q_ = 0; q_ < 2; ++q_) {                                           \
            const int s_ = q_ * 256 + tid;                                         \
            const int brow_ = s_ >> 2, bkb_ = s_ & 3;                              \
            const unsigned short* g_ = Bf + (size_t)(n0 + brow_) * 1024 + (kk) + bkb_ * 8; \
            unsigned short* d_ = &Bfs[buf][(q_ * 256 + w * 64) * 8];               \
            __builtin_amdgcn_global_load_lds(                                      \
                (const __attribute__((address_space(1))) void*)g_,                 \
                (__attribute__((address_space(3))) void*)d_, 16, 0, 0);            \
        }                                                                          \
    } while (0)

#define CONVA(xa_, xb_, xc_, xd_, buf) do {                                       \
        float xf_[16] = {(xa_).x, (xa_).y, (xa_).z, (xa_).w,                       \
                         (xb_).x, (xb_).y, (xb_).z, (xb_).w,                       \
                         (xc_).x, (xc_).y, (xc_).z, (xc_).w,                       \
                         (xd_).x, (xd_).y, (xd_).z, (xd_).w};                      \
        u16x8 v0_, v1_;                                                            \
        _Pragma("unroll")                                                          \
        for (int i_ = 0; i_ < 8; ++i_) v0_[i_] = f2h(xf_[i_]);                     \
        _Pragma("unroll")                                                          \
        for (int i_ = 0; i_ < 8; ++i_) v1_[i_] = f2h(xf_[8 + i_]);                 \
        *(u16x8*)(&Ah[buf][aoff]) = v0_;                                           \
        *(u16x8*)(&Ah[buf][aoff + 8]) = v1_;                                       \
    } while (0)

#define COMPUTE(buf) do {                                                         \
        half8 am_[4], bn_[4];                                                      \
        _Pragma("unroll")                                                          \
        for (int m_ = 0; m_ < 4; ++m_)                                             \
            am_[m_] = *(half8*)(&Ah[buf][(wr * 64 + m_ * 16 + fr) * 32 + fq * 8]); \
        _Pragma("unroll")                                                          \
        for (int n_ = 0; n_ < 4; ++n_)                                             \
            bn_[n_] = *(half8*)(&Bfs[buf][(wc * 64 + n_ * 16 + fr) * 32 + fq * 8]);\
        _Pragma("unroll")                                                          \
        for (int m_ = 0; m_ < 4; ++m_)                                             \
            _Pragma("unroll")                                                      \
            for (int n_ = 0; n_ < 4; ++n_)                                         \
                acc[m_][n_] = __builtin_amdgcn_mfma_f32_16x16x32_f16(am_[m_], bn_[n_], acc[m_][n_], 0, 0, 0); \
    } while (0)

#define PIPE_BAR4() asm volatile("s_waitcnt vmcnt(4) lgkmcnt(0)\n\ts_barrier" ::: "memory")
#define PIPE_BAR0() asm volatile("s_waitcnt vmcnt(0) lgkmcnt(0)\n\ts_barrier" ::: "memory")

    float4 x0a, x0b, x0c, x0d, x1a, x1b, x1c, x1d;

    // ---- prologue: X(0) loads, B(0) gloads, convert X(0)->Ah[0], X(1) loads
    x0a = *(const float4*)(xs);
    x0b = *(const float4*)(xs + 4);
    x0c = *(const float4*)(xs + 8);
    x0d = *(const float4*)(xs + 12);
    __builtin_amdgcn_sched_barrier(0);
    GLDB(0, 0);
    __builtin_amdgcn_sched_barrier(0);
    CONVA(x0a, x0b, x0c, x0d, 0);       // waits X(0); B(0) stays in flight
    x1a = *(const float4*)(xs + 32);
    x1b = *(const float4*)(xs + 36);
    x1c = *(const float4*)(xs + 40);
    x1d = *(const float4*)(xs + 44);
    PIPE_BAR4();                        // drains B(0); X(1) crosses barrier

    // ---- main loop: steps t=0..29 as 15 double-steps
    for (int kk = 0; kk < 928; kk += 64) {
        // even step t = kk/32 : cur=0
        GLDB(kk + 32, 1);
        __builtin_amdgcn_sched_barrier(0);
        x0a = *(const float4*)(xs + kk + 64);
        x0b = *(const float4*)(xs + kk + 68);
        x0c = *(const float4*)(xs + kk + 72);
        x0d = *(const float4*)(xs + kk + 76);
        __builtin_amdgcn_sched_barrier(0);
        COMPUTE(0);
        CONVA(x1a, x1b, x1c, x1d, 1);   // X(t+1) -> Ah[1]
        PIPE_BAR4();                    // drains B(t+1); X(t+2) in flight

        // odd step t+1 : cur=1
        GLDB(kk + 64, 0);
        __builtin_amdgcn_sched_barrier(0);
        x1a = *(const float4*)(xs + kk + 96);
        x1b = *(const float4*)(xs + kk + 100);
        x1c = *(const float4*)(xs + kk + 104);
        x1d = *(const float4*)(xs + kk + 108);
        __builtin_amdgcn_sched_barrier(0);
        COMPUTE(1);
        CONVA(x0a, x0b, x0c, x0d, 0);   // X(t+2) -> Ah[0]
        PIPE_BAR4();
    }

    // ---- tail: t=30 (cur=0), t=31 (cur=1)
    GLDB(992, 1);
    __builtin_amdgcn_sched_barrier(0);
    COMPUTE(0);                          // col 960
    CONVA(x1a, x1b, x1c, x1d, 1);        // X col 992 -> Ah[1]
    PIPE_BAR0();                         // drain everything (last stage)
    COMPUTE(1);                          // col 992

#undef GLDB
#undef CONVA
#undef COMPUTE
#undef PIPE_BAR4
#undef PIPE_BAR0

    // ---- epilogue: C/D layout col=lane&15, row=(lane>>4)*4+reg
    if (nt < 8) {
        const int b_ = (mt * 128) >> 9;
        const int jb0 = (mt & 3) * 128;
        unsigned short* vtw = Vt + (size_t)(nt * 16 + b_) * 128 * 512;
        #pragma unroll
        for (int m = 0; m < 4; ++m) {
            const int jb = jb0 + wr * 64 + m * 16 + fq * 4;
            float mk[4];
            #pragma unroll
            for (int r = 0; r < 4; ++r)
                mk[r] = nm[m0 + wr * 64 + m * 16 + fq * 4 + r];
            #pragma unroll
            for (int n = 0; n < 4; ++n) {
                const int d = wc * 64 + n * 16 + fr;
                u16x4 pk;
                #pragma unroll
                for (int r = 0; r < 4; ++r) pk[r] = f2h(acc[m][n][r] * mk[r]);
                *(u16x4*)(vtw + (size_t)d * 512 + jb) = pk;
            }
        }
    } else {
        #pragma unroll
        for (int m = 0; m < 4; ++m) {
            #pragma unroll
            for (int r = 0; r < 4; ++r) {
                const int R = m0 + wr * 64 + m * 16 + fq * 4 + r;
                #pragma unroll
                for (int n = 0; n < 4; ++n) {
                    const int c = wc * 64 + n * 16 + fr;
                    if (c < 48) LR[(size_t)c * 8192 + R] = acc[m][n][r];
                }
            }
        }
    }
}

// ---------------------------------------------------------------------------
// Kernel 4: fused attn — r22/r24-exact (verified): P single fp16,
//   16 MFMA/step, __syncthreads in-loop (r24's verified form).
// ---------------------------------------------------------------------------
__global__ __launch_bounds__(256, 4) void attn_kernel(const unsigned short* __restrict__ Vt,
                                                      const float* __restrict__ LR,
                                                      const unsigned char* __restrict__ adjB,
                                                      float* __restrict__ out) {
    __shared__ __align__(16) unsigned short Vb[2][16 * 512];
    __shared__ __align__(16) float rt[3 * 512];

    const int bid = blockIdx.x;
    const int itg = bid >> 7, hb = bid & 127, h = hb >> 4, b = hb & 15;
    const int tid = threadIdx.x, w = tid >> 6, lane = tid & 63;
    const int fr = lane & 15, fq = lane >> 4;
    const int i0 = (itg * 4 + w) * 16;
    const int fq8 = fq * 8;

    for (int idx = tid; idx < 1536; idx += 256) {
        int t = idx >> 9, j = idx & 511;
        rt[idx] = LR[(size_t)(24 + t * 8 + h) * 8192 + b * 512 + j];
    }
    const float lf0 = LR[(size_t)(h) * 8192 + b * 512 + i0 + fr];
    const float lf1 = LR[(size_t)(8 + h) * 8192 + b * 512 + i0 + fr];
    const float lf2 = LR[(size_t)(16 + h) * 8192 + b * 512 + i0 + fr];
    const unsigned char* arow = adjB + (size_t)(b * 512 + i0 + fr) * 512;
    const unsigned short* vt = Vt + (size_t)(h * 16 + b) * 128 * 512;

#define STAGE_V(bufp, os_) do {                                                   \
        _Pragma("unroll")                                                          \
        for (int q_ = 0; q_ < 4; ++q_) {                                           \
            const int nh_ = q_ * 4 + w;                                            \
            const unsigned short* src_ = vt + (size_t)((nh_ >> 1) * 16 + fr) * 512 \
                                          + (os_) * 64 + (nh_ & 1) * 32 + fq8;     \
            unsigned short* dst_ = (bufp) + nh_ * 512;                             \
            __builtin_amdgcn_global_load_lds(                                      \
                (const __attribute__((address_space(1))) void*)src_,               \
                (__attribute__((address_space(3))) void*)dst_, 16, 0, 0);          \
        }                                                                          \
    } while (0)

    STAGE_V(&Vb[0][0], 0);
    uint2 aA = *(const uint2*)(arow + fq8);
    uint2 aB = *(const uint2*)(arow + fq8 + 32);

    f32x4 acc[8];
    #pragma unroll
    for (int n = 0; n < 8; ++n) acc[n] = (f32x4){0.f, 0.f, 0.f, 0.f};
    float rsum = 0.f;

    __syncthreads();

    #pragma unroll 1
    for (int os = 0; os < 8; ++os) {
        unsigned short* vb = &Vb[os & 1][0];
        if (os < 7) STAGE_V(&Vb[(os & 1) ^ 1][0], os + 1);

        const int jA = os * 64 + fq8;
        const int jB = jA + 32;

        u16x8 vhA, vhB;
        {
            float4 r0a = *(const float4*)(rt + jA), r0b = *(const float4*)(rt + jA + 4);
            float4 r1a = *(const float4*)(rt + 512 + jA), r1b = *(const float4*)(rt + 512 + jA + 4);
            float4 r2a = *(const float4*)(rt + 1024 + jA), r2b = *(const float4*)(rt + 1024 + jA + 4);
            float e0[8] = {r0a.x, r0a.y, r0a.z, r0a.w, r0b.x, r0b.y, r0b.z, r0b.w};
            float e1[8] = {r1a.x, r1a.y, r1a.z, r1a.w, r1b.x, r1b.y, r1b.z, r1b.w};
            float e2[8] = {r2a.x, r2a.y, r2a.z, r2a.w, r2b.x, r2b.y, r2b.z, r2b.w};
            #pragma unroll
            for (int q = 0; q < 8; ++q) {
                unsigned av = ((q < 4 ? aA.x : aA.y) >> (8 * (q & 3))) & 255u;
                float sb = (av == 1u) ? (lf0 + e0[q])
                         : (av == 2u) ? (lf1 + e1[q]) : (lf2 + e2[q]);
                float sv = fmaxf(sb, 0.f) + 0.2f * fminf(sb, 0.f);
                float p = (av != 0u) ? __expf(sv) : 0.f;
                rsum += p;
                vhA[q] = f2h(p);
            }
        }
        {
            float4 r0a = *(const float4*)(rt + jB), r0b = *(const float4*)(rt + jB + 4);
            float4 r1a = *(const float4*)(rt + 512 + jB), r1b = *(const float4*)(rt + 512 + jB + 4);
            float4 r2a = *(const float4*)(rt + 1024 + jB), r2b = *(const float4*)(rt + 1024 + jB + 4);
            float e0[8] = {r0a.x, r0a.y, r0a.z, r0a.w, r0b.x, r0b.y, r0b.z, r0b.w};
            float e1[8] = {r1a.x, r1a.y, r1a.z, r1a.w, r1b.x, r1b.y, r1b.z, r1b.w};
            float e2[8] = {r2a.x, r2a.y, r2a.z, r2a.w, r2b.x, r2b.y, r2b.z, r2b.w};
            #pragma unroll
            for (int q = 0; q < 8; ++q) {
                unsigned av = ((q < 4 ? aB.x : aB.y) >> (8 * (q & 3))) & 255u;
                float sb = (av == 1u) ? (lf0 + e0[q])
                         : (av == 2u) ? (lf1 + e1[q]) : (lf2 + e2[q]);
                float sv = fmaxf(sb, 0.f) + 0.2f * fminf(sb, 0.f);
                float p = (av != 0u) ? __expf(sv) : 0.f;
                rsum += p;
                vhB[q] = f2h(p);
            }
        }
        if (os < 7) {
            aA = *(const uint2*)(arow + (os + 1) * 64 + fq8);
            aB = *(const uint2*)(arow + (os + 1) * 64 + fq8 + 32);
        }

        half8 ahA = *(half8*)&vhA, ahB = *(half8*)&vhB;

        #pragma unroll
        for (int n = 0; n < 8; ++n) {
            half8 vA = *(half8*)(vb + (n * 2 + 0) * 512 + lane * 8);
            half8 vB = *(half8*)(vb + (n * 2 + 1) * 512 + lane * 8);
            acc[n] = __builtin_amdgcn_mfma_f32_16x16x32_f16(ahA, vA, acc[n], 0, 0, 0);
            acc[n] = __builtin_amdgcn_mfma_f32_16x16x32_f16(ahB, vB, acc[n], 0, 0, 0);
        }
        __syncthreads();
    }
#undef STAGE_V

    rsum += __shfl_xor(rsum, 16);
    rsum += __shfl_xor(rsum, 32);

    #pragma unroll
    for (int rr = 0; rr < 4; ++rr) {
        const int row = fq * 4 + rr;
        const float inv = 1.0f / __shfl(rsum, row);
        #pragma unroll
        for (int n = 0; n < 8; ++n) {
            out[(size_t)(b * 512 + i0 + row) * 1024 + h * 128 + n * 16 + fr] =
                fmaxf(acc[n][rr] * inv, 0.f);
        }
    }
}

// ---------------------------------------------------------------------------
extern "C" void kernel_launch(void* const* d_in, const int* in_sizes, int n_in,
                              void* d_out, int out_size, void* d_ws, size_t ws_size,
                              hipStream_t stream) {
    const float* x   = (const float*)d_in[0];
    const int*   adj = (const int*)d_in[1];
    const float* nm  = (const float*)d_in[2];
    const float* W   = (const float*)d_in[3];
    const float* a1  = (const float*)d_in[4];
    const float* a2  = (const float*)d_in[5];
    float* out = (float*)d_out;
    char* wsb = (char*)d_ws;

    unsigned short* Bf   = (unsigned short*)(wsb);
    float*          LR   = (float*)(wsb + 21495808);
    unsigned short* Vt   = (unsigned short*)(wsb + 23068672);
    unsigned char*  adjB = (unsigned char*)(wsb + 39845888);

    hipLaunchKernelGGL(prep_kernel, dim3(1616), dim3(256), 0, stream, adj, W, a1, a2, Bf, adjB);
    hipLaunchKernelGGL(mgemm, dim3(576), dim3(256), 0, stream, x, Bf, nm, Vt, LR);
    hipLaunchKernelGGL(attn_kernel, dim3(1024), dim3(256), 0, stream, Vt, LR, adjB, out);
}